// Round 4
// baseline (3502.373 us; speedup 1.0000x reference)
//
#include <hip/hip_runtime.h>

typedef unsigned short u16;
typedef __attribute__((ext_vector_type(8))) short short8;
typedef __attribute__((ext_vector_type(4))) float f32x4;

#define HDIM 128

__device__ __forceinline__ float bf2f(u16 v) {
    return __uint_as_float(((unsigned int)v) << 16);
}
__device__ __forceinline__ u16 f2bf(float f) {
    unsigned int u = __float_as_uint(f);
    unsigned int r = (u + 0x7FFFu + ((u >> 16) & 1u)) >> 16;  // RNE
    return (u16)r;
}

// ---- transpose + bf16-ify conv weights: wt[mat][n*128+k] = bf16(w[mat][k*128+n])
//      mats 0..2 = w1 layers, 3..5 = w2 layers   (inputs fp32)
__global__ __launch_bounds__(256) void transpose_w_kernel(
    const float* __restrict__ w1, const float* __restrict__ w2, u16* __restrict__ wt)
{
    int gid = blockIdx.x * 256 + threadIdx.x;   // 6 * 16384 total
    int mat = gid >> 14;
    int idx = gid & 16383;
    int n = idx >> 7, k = idx & 127;
    const float* src = (mat < 3) ? (w1 + mat * 16384) : (w2 + (mat - 3) * 16384);
    wt[gid] = f2bf(src[k * 128 + n]);
}

// ---- x0 = bf16(atom_emb[clip(types)])  (fp32 source, 8 cols/thread)
__global__ __launch_bounds__(256) void embed_kernel(
    const int* __restrict__ types, const float* __restrict__ emb,
    u16* __restrict__ x, int N)
{
    int gid = blockIdx.x * 256 + threadIdx.x;   // N*16
    if (gid >= N * 16) return;
    int n = gid >> 4, c8 = (gid & 15) * 8;
    int t = types[n];
    t = t < 0 ? 0 : (t > 119 ? 119 : t);
    float4 a = *(const float4*)(emb + (size_t)t * 128 + c8);
    float4 b = *(const float4*)(emb + (size_t)t * 128 + c8 + 4);
    uint4 ov;
    u16* op = (u16*)&ov;
    op[0] = f2bf(a.x); op[1] = f2bf(a.y); op[2] = f2bf(a.z); op[3] = f2bf(a.w);
    op[4] = f2bf(b.x); op[5] = f2bf(b.y); op[6] = f2bf(b.z); op[7] = f2bf(b.w);
    *(uint4*)(x + (size_t)n * 128 + c8) = ov;
}

// ---- edge messages: agg[dst] += relu(x[src] + bond_emb[etype]), 16 lanes (8 cols each) per edge
__global__ __launch_bounds__(256) void msg_kernel(
    const u16* __restrict__ x, const int* __restrict__ edges,
    const int* __restrict__ etypes, const float* __restrict__ bond_emb,
    float* __restrict__ agg, int E, int N)
{
    __shared__ __align__(16) float bs[5 * 128];
    for (int i = threadIdx.x; i < 5 * 128; i += 256) bs[i] = bond_emb[i];
    __syncthreads();
    int gid = blockIdx.x * 256 + threadIdx.x;
    int e = gid >> 4;
    if (e >= E) return;
    int c8 = (gid & 15) * 8;
    int s = edges[e], d = edges[E + e], t = etypes[e];
    s = s < 0 ? 0 : (s >= N ? N - 1 : s);
    d = d < 0 ? 0 : (d >= N ? N - 1 : d);
    t = t < 0 ? 0 : (t > 4 ? 4 : t);
    uint4 xv4 = *(const uint4*)(x + (size_t)s * 128 + c8);
    const u16* xp = (const u16*)&xv4;
    const float* bp = bs + t * 128 + c8;
    float* ap = agg + (size_t)d * 128 + c8;
#pragma unroll
    for (int i = 0; i < 8; i++) {
        float m = bf2f(xp[i]) + bp[i];
        if (m > 0.f) atomicAdd(ap + i, m);   // relu; zero adds are no-ops -> skip
    }
}

// ---- fused GINE MLP: x = relu((x+agg) @ W1 + b1) @ W2 + b2   (in-place on bf16 x, 64 rows/block)
__global__ __launch_bounds__(256) void mlp_kernel(
    u16* __restrict__ x, const float* __restrict__ agg,
    const u16* __restrict__ w1t, const float* __restrict__ b1,
    const u16* __restrict__ w2t, const float* __restrict__ b2, int N)
{
    __shared__ __align__(16) u16 As[64][136];    // A-tile (bf16), +8 pad
    __shared__ __align__(16) u16 Ws[128][136];   // W^T (n-major, bf16), +8 pad
    const int tid  = threadIdx.x;
    const int row0 = blockIdx.x * 64;
    const int wave = tid >> 6, lane = tid & 63;
    const int m = lane & 15, quad = lane >> 4;

    // stage W1^T -> Ws (16B chunks)
    {
        const uint4* src = (const uint4*)w1t;    // 2048 x 16B
        for (int i = tid; i < 2048; i += 256) {
            int n = i >> 4, k8 = i & 15;
            *(uint4*)&Ws[n][k8 * 8] = src[i];
        }
    }
    // stage A = bf16(x + agg)
    for (int i = tid; i < 1024; i += 256) {      // 64 rows x 16 col-chunks of 8
        int r = i >> 4, c8 = (i & 15) * 8;
        int row = row0 + r;
        uint4 ov = make_uint4(0u, 0u, 0u, 0u);
        if (row < N) {
            uint4 xv = *(const uint4*)(x + (size_t)row * 128 + c8);
            const u16* xp = (const u16*)&xv;
            float4 a0 = *(const float4*)(agg + (size_t)row * 128 + c8);
            float4 a1 = *(const float4*)(agg + (size_t)row * 128 + c8 + 4);
            u16* op = (u16*)&ov;
            op[0] = f2bf(bf2f(xp[0]) + a0.x);
            op[1] = f2bf(bf2f(xp[1]) + a0.y);
            op[2] = f2bf(bf2f(xp[2]) + a0.z);
            op[3] = f2bf(bf2f(xp[3]) + a0.w);
            op[4] = f2bf(bf2f(xp[4]) + a1.x);
            op[5] = f2bf(bf2f(xp[5]) + a1.y);
            op[6] = f2bf(bf2f(xp[6]) + a1.z);
            op[7] = f2bf(bf2f(xp[7]) + a1.w);
        }
        *(uint4*)&As[r][c8] = ov;
    }
    __syncthreads();

    // mm1: acc = A @ W1  (each wave: 16 rows x 128 cols)
    f32x4 acc[8];
#pragma unroll
    for (int c = 0; c < 8; c++) acc[c] = (f32x4){0.f, 0.f, 0.f, 0.f};
#pragma unroll
    for (int q = 0; q < 4; q++) {
        short8 a = *(const short8*)&As[wave * 16 + m][q * 32 + quad * 8];
#pragma unroll
        for (int c = 0; c < 8; c++) {
            short8 b = *(const short8*)&Ws[c * 16 + m][q * 32 + quad * 8];
            acc[c] = __builtin_amdgcn_mfma_f32_16x16x32_bf16(a, b, acc[c], 0, 0, 0);
        }
    }
    __syncthreads();   // all waves done reading Ws(W1)

    // stage W2^T -> Ws
    {
        const uint4* src = (const uint4*)w2t;
        for (int i = tid; i < 2048; i += 256) {
            int n = i >> 4, k8 = i & 15;
            *(uint4*)&Ws[n][k8 * 8] = src[i];
        }
    }
    // epilogue mm1: h = relu(acc + b1) -> As (rows wave-private; D layout row=quad*4+r, col=lane&15)
#pragma unroll
    for (int c = 0; c < 8; c++) {
        int col = c * 16 + m;
        float bias = b1[col];
#pragma unroll
        for (int r = 0; r < 4; r++) {
            float v = acc[c][r] + bias;
            v = v > 0.f ? v : 0.f;
            As[wave * 16 + quad * 4 + r][col] = f2bf(v);
        }
    }
    __syncthreads();   // Ws(W2) staged, As(h) written

    // mm2: acc2 = h @ W2
    f32x4 acc2[8];
#pragma unroll
    for (int c = 0; c < 8; c++) acc2[c] = (f32x4){0.f, 0.f, 0.f, 0.f};
#pragma unroll
    for (int q = 0; q < 4; q++) {
        short8 a = *(const short8*)&As[wave * 16 + m][q * 32 + quad * 8];
#pragma unroll
        for (int c = 0; c < 8; c++) {
            short8 b = *(const short8*)&Ws[c * 16 + m][q * 32 + quad * 8];
            acc2[c] = __builtin_amdgcn_mfma_f32_16x16x32_bf16(a, b, acc2[c], 0, 0, 0);
        }
    }
    __syncthreads();   // everyone done reading As(h)

    // epilogue mm2 -> As (bf16), then coalesced store to x
#pragma unroll
    for (int c = 0; c < 8; c++) {
        int col = c * 16 + m;
        float bias = b2[col];
#pragma unroll
        for (int r = 0; r < 4; r++)
            As[wave * 16 + quad * 4 + r][col] = f2bf(acc2[c][r] + bias);
    }
    __syncthreads();
    for (int i = tid; i < 1024; i += 256) {
        int r = i >> 4, c8 = (i & 15) * 8;
        int row = row0 + r;
        if (row < N) *(uint4*)(x + (size_t)row * 128 + c8) = *(const uint4*)&As[r][c8];
    }
}

// ---- fused readout (segment mean over sorted node_batch) + 2-layer proj with SiLU (fp32 out)
__global__ __launch_bounds__(128) void readout_proj_kernel(
    const u16* __restrict__ x, const int* __restrict__ nb,
    const float* __restrict__ pw1, const float* __restrict__ pb1,
    const float* __restrict__ pw2, const float* __restrict__ pb2,
    float* __restrict__ out, int N)
{
    int b = blockIdx.x;
    int c = threadIdx.x;                  // 128 threads, one output column each
    __shared__ int range[2];
    __shared__ float gs[128];
    __shared__ float us[128];
    if (c < 2) {                          // lower_bound(b), lower_bound(b+1)
        int target = b + c;
        int lo = 0, hi = N;
        while (lo < hi) {
            int mid = (lo + hi) >> 1;
            if (nb[mid] < target) lo = mid + 1; else hi = mid;
        }
        range[c] = lo;
    }
    __syncthreads();
    int s = range[0], e = range[1];
    float sum = 0.f;
    for (int n = s; n < e; n++) sum += bf2f(x[(size_t)n * 128 + c]);
    float cnt = (float)((e - s) > 0 ? (e - s) : 1);
    gs[c] = sum / cnt;
    __syncthreads();
    float a1 = pb1[c];
    for (int k = 0; k < 128; k++) a1 += gs[k] * pw1[k * 128 + c];
    float u = a1 / (1.f + __expf(-a1));   // SiLU
    us[c] = u;
    __syncthreads();
    float a2 = pb2[c];
    for (int k = 0; k < 128; k++) a2 += us[k] * pw2[k * 128 + c];
    out[(size_t)b * 128 + c] = a2;        // fp32 output
}

extern "C" void kernel_launch(void* const* d_in, const int* in_sizes, int n_in,
                              void* d_out, int out_size, void* d_ws, size_t ws_size,
                              hipStream_t stream) {
    const int*   atom_types  = (const int*)d_in[0];
    const int*   edges       = (const int*)d_in[1];
    const int*   edge_types  = (const int*)d_in[2];
    const int*   node_batch  = (const int*)d_in[3];
    const float* atom_emb    = (const float*)d_in[4];
    const float* bond_emb    = (const float*)d_in[5];
    const float* conv_w1     = (const float*)d_in[6];
    const float* conv_b1     = (const float*)d_in[7];
    const float* conv_w2     = (const float*)d_in[8];
    const float* conv_b2     = (const float*)d_in[9];
    const float* pw1         = (const float*)d_in[10];
    const float* pb1         = (const float*)d_in[11];
    const float* pw2         = (const float*)d_in[12];
    const float* pb2         = (const float*)d_in[13];
    float* out = (float*)d_out;

    const int N = in_sizes[0];
    const int E = in_sizes[2];
    const int G = out_size / HDIM;

    // workspace carve: x (N*128 bf16), agg (N*128 f32), wt (6*16384 bf16)
    size_t x_bytes   = (size_t)N * HDIM * sizeof(u16);
    size_t agg_bytes = (size_t)N * HDIM * sizeof(float);
    size_t wt_bytes  = (size_t)6 * HDIM * HDIM * sizeof(u16);
    if (ws_size < x_bytes + agg_bytes + wt_bytes) {
        // diagnostic fallback: finite absmax == max|ref| signals "ws too small"
        hipMemsetAsync(d_out, 0, (size_t)out_size * sizeof(float), stream);
        return;
    }
    u16*   x   = (u16*)d_ws;
    float* agg = (float*)((char*)d_ws + x_bytes);
    u16*   wt  = (u16*)((char*)d_ws + x_bytes + agg_bytes);

    transpose_w_kernel<<<(6 * 16384) / 256, 256, 0, stream>>>(conv_w1, conv_w2, wt);
    embed_kernel<<<(N * 16 + 255) / 256, 256, 0, stream>>>(atom_types, atom_emb, x, N);

    for (int l = 0; l < 3; l++) {
        hipMemsetAsync(agg, 0, agg_bytes, stream);
        msg_kernel<<<(E * 16 + 255) / 256, 256, 0, stream>>>(x, edges, edge_types, bond_emb, agg, E, N);
        mlp_kernel<<<(N + 63) / 64, 256, 0, stream>>>(
            x, agg, wt + l * 16384, conv_b1 + l * 128,
            wt + (3 + l) * 16384, conv_b2 + l * 128, N);
    }

    readout_proj_kernel<<<G, 128, 0, stream>>>(x, node_batch, pw1, pb1, pw2, pb2, out, N);
}

// Round 5
// 437.717 us; speedup vs baseline: 8.0015x; 8.0015x over previous
//
#include <hip/hip_runtime.h>

typedef unsigned short u16;
typedef __attribute__((ext_vector_type(8))) short short8;
typedef __attribute__((ext_vector_type(4))) float f32x4;

#define HDIM 128
#define SCAN_B 512

__device__ __forceinline__ float bf2f(u16 v) {
    return __uint_as_float(((unsigned int)v) << 16);
}
__device__ __forceinline__ u16 f2bf(float f) {
    unsigned int u = __float_as_uint(f);
    unsigned int r = (u + 0x7FFFu + ((u >> 16) & 1u)) >> 16;  // RNE
    return (u16)r;
}

// ---- transpose + bf16-ify conv weights: wt[mat][n*128+k] = bf16(w[mat][k*128+n])
__global__ __launch_bounds__(256) void transpose_w_kernel(
    const float* __restrict__ w1, const float* __restrict__ w2, u16* __restrict__ wt)
{
    int gid = blockIdx.x * 256 + threadIdx.x;   // 6 * 16384
    int mat = gid >> 14;
    int idx = gid & 16383;
    int n = idx >> 7, k = idx & 127;
    const float* src = (mat < 3) ? (w1 + mat * 16384) : (w2 + (mat - 3) * 16384);
    wt[gid] = f2bf(src[k * 128 + n]);
}

// ---- x0 = bf16(atom_emb[clip(types)])
__global__ __launch_bounds__(256) void embed_kernel(
    const int* __restrict__ types, const float* __restrict__ emb,
    u16* __restrict__ x, int N)
{
    int gid = blockIdx.x * 256 + threadIdx.x;   // N*16
    if (gid >= N * 16) return;
    int n = gid >> 4, c8 = (gid & 15) * 8;
    int t = types[n];
    t = t < 0 ? 0 : (t > 119 ? 119 : t);
    float4 a = *(const float4*)(emb + (size_t)t * 128 + c8);
    float4 b = *(const float4*)(emb + (size_t)t * 128 + c8 + 4);
    uint4 ov;
    u16* op = (u16*)&ov;
    op[0] = f2bf(a.x); op[1] = f2bf(a.y); op[2] = f2bf(a.z); op[3] = f2bf(a.w);
    op[4] = f2bf(b.x); op[5] = f2bf(b.y); op[6] = f2bf(b.z); op[7] = f2bf(b.w);
    *(uint4*)(x + (size_t)n * 128 + c8) = ov;
}

// ============ CSR build (once per launch; edges are layer-invariant) ============

// deg[dst]++ for each edge
__global__ __launch_bounds__(256) void deg_hist_kernel(
    const int* __restrict__ edges, int* __restrict__ deg, int E, int N)
{
    int e = blockIdx.x * 256 + threadIdx.x;
    if (e >= E) return;
    int d = edges[E + e];
    d = d < 0 ? 0 : (d >= N ? N - 1 : d);
    atomicAdd(&deg[d], 1);
}

// per-block exclusive scan of deg -> offs (local), block totals -> bsum
__global__ __launch_bounds__(SCAN_B) void scan_block_kernel(
    const int* __restrict__ deg, int* __restrict__ offs, int* __restrict__ bsum, int N)
{
    __shared__ int tmp[SCAN_B];
    int t = threadIdx.x;
    int gid = blockIdx.x * SCAN_B + t;
    int v = (gid < N) ? deg[gid] : 0;
    tmp[t] = v;
    __syncthreads();
#pragma unroll
    for (int off = 1; off < SCAN_B; off <<= 1) {
        int add = (t >= off) ? tmp[t - off] : 0;
        __syncthreads();
        tmp[t] += add;
        __syncthreads();
    }
    if (gid < N) offs[gid] = tmp[t] - v;           // exclusive
    if (t == SCAN_B - 1) bsum[blockIdx.x] = tmp[t]; // block total
}

// exclusive scan of block totals (nblk <= 1024; N <= 524288)
__global__ __launch_bounds__(1024) void scan_partials_kernel(int* __restrict__ bsum, int nblk)
{
    __shared__ int tmp[1024];
    int t = threadIdx.x;
    int v = (t < nblk) ? bsum[t] : 0;
    tmp[t] = v;
    __syncthreads();
#pragma unroll
    for (int off = 1; off < 1024; off <<= 1) {
        int add = (t >= off) ? tmp[t - off] : 0;
        __syncthreads();
        tmp[t] += add;
        __syncthreads();
    }
    if (t < nblk) bsum[t] = tmp[t] - v;            // exclusive
}

// offs += scanned block prefix; cursor = offs; offs[N] = E
__global__ __launch_bounds__(256) void finalize_offs_kernel(
    int* __restrict__ offs, const int* __restrict__ bsum,
    int* __restrict__ cursor, int N, int E)
{
    int gid = blockIdx.x * 256 + threadIdx.x;
    if (gid < N) {
        int v = offs[gid] + bsum[gid / SCAN_B];
        offs[gid] = v;
        cursor[gid] = v;
    }
    if (gid == 0) offs[N] = E;
}

// scatter edges into dst-grouped CSR; entry = src*8 + type
__global__ __launch_bounds__(256) void fill_csr_kernel(
    const int* __restrict__ edges, const int* __restrict__ etypes,
    int* __restrict__ cursor, int* __restrict__ csr, int E, int N)
{
    int e = blockIdx.x * 256 + threadIdx.x;
    if (e >= E) return;
    int s = edges[e], d = edges[E + e], t = etypes[e];
    s = s < 0 ? 0 : (s >= N ? N - 1 : s);
    d = d < 0 ? 0 : (d >= N ? N - 1 : d);
    t = t < 0 ? 0 : (t > 4 ? 4 : t);
    int pos = atomicAdd(&cursor[d], 1);
    csr[pos] = (s << 3) | t;
}

// ============ per-layer: gather-aggregate, no atomics ============
// xa[n] = bf16( x[n] + sum_{j in in(n)} relu(x[src_j] + bond[type_j]) )
__global__ __launch_bounds__(256) void agg_kernel(
    const u16* __restrict__ x, const int* __restrict__ offs,
    const int* __restrict__ csr, const float* __restrict__ bond_emb,
    u16* __restrict__ xa, int N)
{
    __shared__ __align__(16) float bs[5 * 128];
    for (int i = threadIdx.x; i < 5 * 128; i += 256) bs[i] = bond_emb[i];
    __syncthreads();
    int n = blockIdx.x * 16 + (threadIdx.x >> 4);   // 16 nodes/block, 16 lanes/node
    if (n >= N) return;
    int c8 = (threadIdx.x & 15) * 8;
    float acc[8];
    uint4 xv = *(const uint4*)(x + (size_t)n * 128 + c8);
    const u16* xp = (const u16*)&xv;
#pragma unroll
    for (int i = 0; i < 8; i++) acc[i] = bf2f(xp[i]);
    int s0 = offs[n], s1 = offs[n + 1];
    for (int j = s0; j < s1; j++) {
        int v = csr[j];
        int src = v >> 3, t = v & 7;
        uint4 g = *(const uint4*)(x + (size_t)src * 128 + c8);
        const u16* gp = (const u16*)&g;
        const float* bp = bs + t * 128 + c8;
#pragma unroll
        for (int i = 0; i < 8; i++) {
            float m = bf2f(gp[i]) + bp[i];
            acc[i] += (m > 0.f ? m : 0.f);
        }
    }
    uint4 ov;
    u16* op = (u16*)&ov;
#pragma unroll
    for (int i = 0; i < 8; i++) op[i] = f2bf(acc[i]);
    *(uint4*)(xa + (size_t)n * 128 + c8) = ov;
}

// ---- fused GINE MLP: x = relu(xa @ W1 + b1) @ W2 + b2   (reads bf16 xa, writes bf16 x)
__global__ __launch_bounds__(256) void mlp_kernel(
    u16* __restrict__ x, const u16* __restrict__ xa,
    const u16* __restrict__ w1t, const float* __restrict__ b1,
    const u16* __restrict__ w2t, const float* __restrict__ b2, int N)
{
    __shared__ __align__(16) u16 As[64][136];    // A-tile (bf16), +8 pad
    __shared__ __align__(16) u16 Ws[128][136];   // W^T (n-major, bf16), +8 pad
    const int tid  = threadIdx.x;
    const int row0 = blockIdx.x * 64;
    const int wave = tid >> 6, lane = tid & 63;
    const int m = lane & 15, quad = lane >> 4;

    // stage W1^T -> Ws
    {
        const uint4* src = (const uint4*)w1t;    // 2048 x 16B
        for (int i = tid; i < 2048; i += 256) {
            int n = i >> 4, k8 = i & 15;
            *(uint4*)&Ws[n][k8 * 8] = src[i];
        }
    }
    // stage A = xa tile (already bf16)
    for (int i = tid; i < 1024; i += 256) {      // 64 rows x 16 chunks of 8
        int r = i >> 4, c8 = (i & 15) * 8;
        int row = row0 + r;
        uint4 ov = make_uint4(0u, 0u, 0u, 0u);
        if (row < N) ov = *(const uint4*)(xa + (size_t)row * 128 + c8);
        *(uint4*)&As[r][c8] = ov;
    }
    __syncthreads();

    // mm1: acc = A @ W1
    f32x4 acc[8];
#pragma unroll
    for (int c = 0; c < 8; c++) acc[c] = (f32x4){0.f, 0.f, 0.f, 0.f};
#pragma unroll
    for (int q = 0; q < 4; q++) {
        short8 a = *(const short8*)&As[wave * 16 + m][q * 32 + quad * 8];
#pragma unroll
        for (int c = 0; c < 8; c++) {
            short8 b = *(const short8*)&Ws[c * 16 + m][q * 32 + quad * 8];
            acc[c] = __builtin_amdgcn_mfma_f32_16x16x32_bf16(a, b, acc[c], 0, 0, 0);
        }
    }
    __syncthreads();   // done reading Ws(W1)

    // stage W2^T -> Ws
    {
        const uint4* src = (const uint4*)w2t;
        for (int i = tid; i < 2048; i += 256) {
            int n = i >> 4, k8 = i & 15;
            *(uint4*)&Ws[n][k8 * 8] = src[i];
        }
    }
    // epilogue mm1: h = relu(acc + b1) -> As (D layout: row=quad*4+r, col=lane&15)
#pragma unroll
    for (int c = 0; c < 8; c++) {
        int col = c * 16 + m;
        float bias = b1[col];
#pragma unroll
        for (int r = 0; r < 4; r++) {
            float v = acc[c][r] + bias;
            v = v > 0.f ? v : 0.f;
            As[wave * 16 + quad * 4 + r][col] = f2bf(v);
        }
    }
    __syncthreads();

    // mm2: acc2 = h @ W2
    f32x4 acc2[8];
#pragma unroll
    for (int c = 0; c < 8; c++) acc2[c] = (f32x4){0.f, 0.f, 0.f, 0.f};
#pragma unroll
    for (int q = 0; q < 4; q++) {
        short8 a = *(const short8*)&As[wave * 16 + m][q * 32 + quad * 8];
#pragma unroll
        for (int c = 0; c < 8; c++) {
            short8 b = *(const short8*)&Ws[c * 16 + m][q * 32 + quad * 8];
            acc2[c] = __builtin_amdgcn_mfma_f32_16x16x32_bf16(a, b, acc2[c], 0, 0, 0);
        }
    }
    __syncthreads();

    // epilogue mm2 -> As (bf16), then coalesced store to x
#pragma unroll
    for (int c = 0; c < 8; c++) {
        int col = c * 16 + m;
        float bias = b2[col];
#pragma unroll
        for (int r = 0; r < 4; r++)
            As[wave * 16 + quad * 4 + r][col] = f2bf(acc2[c][r] + bias);
    }
    __syncthreads();
    for (int i = tid; i < 1024; i += 256) {
        int r = i >> 4, c8 = (i & 15) * 8;
        int row = row0 + r;
        if (row < N) *(uint4*)(x + (size_t)row * 128 + c8) = *(const uint4*)&As[r][c8];
    }
}

// ---- fused readout (segment mean over sorted node_batch) + proj (fp32 out)
__global__ __launch_bounds__(128) void readout_proj_kernel(
    const u16* __restrict__ x, const int* __restrict__ nb,
    const float* __restrict__ pw1, const float* __restrict__ pb1,
    const float* __restrict__ pw2, const float* __restrict__ pb2,
    float* __restrict__ out, int N)
{
    int b = blockIdx.x;
    int c = threadIdx.x;
    __shared__ int range[2];
    __shared__ float gs[128];
    __shared__ float us[128];
    if (c < 2) {
        int target = b + c;
        int lo = 0, hi = N;
        while (lo < hi) {
            int mid = (lo + hi) >> 1;
            if (nb[mid] < target) lo = mid + 1; else hi = mid;
        }
        range[c] = lo;
    }
    __syncthreads();
    int s = range[0], e = range[1];
    float sum = 0.f;
    for (int n = s; n < e; n++) sum += bf2f(x[(size_t)n * 128 + c]);
    float cnt = (float)((e - s) > 0 ? (e - s) : 1);
    gs[c] = sum / cnt;
    __syncthreads();
    float a1 = pb1[c];
    for (int k = 0; k < 128; k++) a1 += gs[k] * pw1[k * 128 + c];
    float u = a1 / (1.f + __expf(-a1));   // SiLU
    us[c] = u;
    __syncthreads();
    float a2 = pb2[c];
    for (int k = 0; k < 128; k++) a2 += us[k] * pw2[k * 128 + c];
    out[(size_t)b * 128 + c] = a2;
}

extern "C" void kernel_launch(void* const* d_in, const int* in_sizes, int n_in,
                              void* d_out, int out_size, void* d_ws, size_t ws_size,
                              hipStream_t stream) {
    const int*   atom_types  = (const int*)d_in[0];
    const int*   edges       = (const int*)d_in[1];
    const int*   edge_types  = (const int*)d_in[2];
    const int*   node_batch  = (const int*)d_in[3];
    const float* atom_emb    = (const float*)d_in[4];
    const float* bond_emb    = (const float*)d_in[5];
    const float* conv_w1     = (const float*)d_in[6];
    const float* conv_b1     = (const float*)d_in[7];
    const float* conv_w2     = (const float*)d_in[8];
    const float* conv_b2     = (const float*)d_in[9];
    const float* pw1         = (const float*)d_in[10];
    const float* pb1         = (const float*)d_in[11];
    const float* pw2         = (const float*)d_in[12];
    const float* pb2         = (const float*)d_in[13];
    float* out = (float*)d_out;

    const int N = in_sizes[0];
    const int E = in_sizes[2];
    const int G = out_size / HDIM;
    const int nblk = (N + SCAN_B - 1) / SCAN_B;   // <= 1024 for N <= 524288

    // workspace carve
    size_t x_bytes   = (size_t)N * HDIM * sizeof(u16);
    size_t xa_bytes  = (size_t)N * HDIM * sizeof(u16);
    size_t wt_bytes  = (size_t)6 * HDIM * HDIM * sizeof(u16);
    size_t deg_bytes = (size_t)N * 4;
    size_t off_bytes = (size_t)(N + 1) * 4;
    size_t cur_bytes = (size_t)N * 4;
    size_t bs_bytes  = 1024 * 4;
    size_t csr_bytes = (size_t)E * 4;
    size_t need = x_bytes + xa_bytes + wt_bytes + deg_bytes + off_bytes + cur_bytes + bs_bytes + csr_bytes;
    if (ws_size < need) {
        hipMemsetAsync(d_out, 0, (size_t)out_size * sizeof(float), stream);
        return;
    }
    char* p = (char*)d_ws;
    u16* x    = (u16*)p;            p += x_bytes;
    u16* xa   = (u16*)p;            p += xa_bytes;
    u16* wt   = (u16*)p;            p += wt_bytes;
    int* deg  = (int*)p;            p += deg_bytes;
    int* offs = (int*)p;            p += off_bytes;
    int* cur  = (int*)p;            p += cur_bytes;
    int* bsum = (int*)p;            p += bs_bytes;
    int* csr  = (int*)p;

    // weights + embedding
    transpose_w_kernel<<<(6 * 16384) / 256, 256, 0, stream>>>(conv_w1, conv_w2, wt);
    embed_kernel<<<(N * 16 + 255) / 256, 256, 0, stream>>>(atom_types, atom_emb, x, N);

    // CSR build (once; reused by all 3 layers)
    hipMemsetAsync(deg, 0, deg_bytes, stream);
    deg_hist_kernel<<<(E + 255) / 256, 256, 0, stream>>>(edges, deg, E, N);
    scan_block_kernel<<<nblk, SCAN_B, 0, stream>>>(deg, offs, bsum, N);
    scan_partials_kernel<<<1, 1024, 0, stream>>>(bsum, nblk);
    finalize_offs_kernel<<<(N + 255) / 256, 256, 0, stream>>>(offs, bsum, cur, N, E);
    fill_csr_kernel<<<(E + 255) / 256, 256, 0, stream>>>(edges, edge_types, cur, csr, E, N);

    for (int l = 0; l < 3; l++) {
        agg_kernel<<<(N + 15) / 16, 256, 0, stream>>>(x, offs, csr, bond_emb, xa, N);
        mlp_kernel<<<(N + 63) / 64, 256, 0, stream>>>(
            x, xa, wt + l * 16384, conv_b1 + l * 128,
            wt + (3 + l) * 16384, conv_b2 + l * 128, N);
    }

    readout_proj_kernel<<<G, 128, 0, stream>>>(x, node_batch, pw1, pb1, pw2, pb2, out, N);
}

// Round 6
// 437.094 us; speedup vs baseline: 8.0129x; 1.0014x over previous
//
#include <hip/hip_runtime.h>

typedef unsigned short u16;
typedef __attribute__((ext_vector_type(8))) short short8;
typedef __attribute__((ext_vector_type(4))) float f32x4;

#define HDIM 128
#define SCAN_B 512

__device__ __forceinline__ float bf2f(u16 v) {
    return __uint_as_float(((unsigned int)v) << 16);
}
__device__ __forceinline__ u16 f2bf(float f) {
    unsigned int u = __float_as_uint(f);
    unsigned int r = (u + 0x7FFFu + ((u >> 16) & 1u)) >> 16;  // RNE
    return (u16)r;
}

// ---- prep: transpose+bf16 8 weight mats (0-2 w1, 3-5 w2, 6 pw1, 7 pw2) + bf16 embed table
__global__ __launch_bounds__(256) void prep_kernel(
    const float* __restrict__ w1, const float* __restrict__ w2,
    const float* __restrict__ pw1, const float* __restrict__ pw2,
    const float* __restrict__ atom_emb,
    u16* __restrict__ wt, u16* __restrict__ ebf)
{
    int gid = blockIdx.x * 256 + threadIdx.x;
    if (gid < 8 * 16384) {
        int mat = gid >> 14;
        int idx = gid & 16383;
        int n = idx >> 7, k = idx & 127;
        const float* src;
        if      (mat < 3) src = w1 + mat * 16384;
        else if (mat < 6) src = w2 + (mat - 3) * 16384;
        else if (mat == 6) src = pw1;
        else               src = pw2;
        wt[gid] = f2bf(src[k * 128 + n]);
    } else {
        int i = gid - 8 * 16384;
        if (i < 120 * 128) ebf[i] = f2bf(atom_emb[i]);
    }
}

// ============ CSR build (once; edges layer-invariant) ============
__global__ __launch_bounds__(256) void deg_hist_kernel(
    const int* __restrict__ edges, int* __restrict__ deg, int E, int N)
{
    int e = blockIdx.x * 256 + threadIdx.x;
    if (e >= E) return;
    int d = edges[E + e];
    d = d < 0 ? 0 : (d >= N ? N - 1 : d);
    atomicAdd(&deg[d], 1);
}

__global__ __launch_bounds__(SCAN_B) void scan_block_kernel(
    const int* __restrict__ deg, int* __restrict__ offs, int* __restrict__ bsum, int N)
{
    __shared__ int tmp[SCAN_B];
    int t = threadIdx.x;
    int gid = blockIdx.x * SCAN_B + t;
    int v = (gid < N) ? deg[gid] : 0;
    tmp[t] = v;
    __syncthreads();
#pragma unroll
    for (int off = 1; off < SCAN_B; off <<= 1) {
        int add = (t >= off) ? tmp[t - off] : 0;
        __syncthreads();
        tmp[t] += add;
        __syncthreads();
    }
    if (gid < N) offs[gid] = tmp[t] - v;
    if (t == SCAN_B - 1) bsum[blockIdx.x] = tmp[t];
}

__global__ __launch_bounds__(1024) void scan_partials_kernel(int* __restrict__ bsum, int nblk)
{
    __shared__ int tmp[1024];
    int t = threadIdx.x;
    int v = (t < nblk) ? bsum[t] : 0;
    tmp[t] = v;
    __syncthreads();
#pragma unroll
    for (int off = 1; off < 1024; off <<= 1) {
        int add = (t >= off) ? tmp[t - off] : 0;
        __syncthreads();
        tmp[t] += add;
        __syncthreads();
    }
    if (t < nblk) bsum[t] = tmp[t] - v;
}

__global__ __launch_bounds__(256) void finalize_offs_kernel(
    int* __restrict__ offs, const int* __restrict__ bsum,
    int* __restrict__ cursor, int N, int E)
{
    int gid = blockIdx.x * 256 + threadIdx.x;
    if (gid < N) {
        int v = offs[gid] + bsum[gid / SCAN_B];
        offs[gid] = v;
        cursor[gid] = v;
    }
    if (gid == 0) offs[N] = E;
}

__global__ __launch_bounds__(256) void fill_csr_kernel(
    const int* __restrict__ edges, const int* __restrict__ etypes,
    int* __restrict__ cursor, int* __restrict__ csr, int E, int N)
{
    int e = blockIdx.x * 256 + threadIdx.x;
    if (e >= E) return;
    int s = edges[e], d = edges[E + e], t = etypes[e];
    s = s < 0 ? 0 : (s >= N ? N - 1 : s);
    d = d < 0 ? 0 : (d >= N ? N - 1 : d);
    t = t < 0 ? 0 : (t > 4 ? 4 : t);
    int pos = atomicAdd(&cursor[d], 1);
    csr[pos] = (s << 3) | t;
}

// ============ fused GINE layer: gather-agg -> MLP, 64 rows/block ============
// x_out = relu( bf16(x_in + sum relu(x_in[src]+bond)) @ W1 + b1 ) @ W2 + b2
// layer 0 (use_emb=1): x_in is virtual: row i = ebf[clip(types[i])]
__global__ __launch_bounds__(256) void gine_kernel(
    const u16* __restrict__ x_in, u16* __restrict__ x_out,
    const int* __restrict__ types, int use_emb, const u16* __restrict__ ebf,
    const int* __restrict__ offs, const int* __restrict__ csr,
    const float* __restrict__ bond_emb,
    const u16* __restrict__ w1t, const float* __restrict__ b1,
    const u16* __restrict__ w2t, const float* __restrict__ b2, int N)
{
    __shared__ __align__(16) u16 As[64][136];    // A-tile, +8 pad
    __shared__ __align__(16) u16 Ws[128][136];   // W^T tile, +8 pad
    __shared__ __align__(16) u16 bsh[5 * 128];   // bond table bf16
    const int tid  = threadIdx.x;
    const int row0 = blockIdx.x * 64;
    const int wave = tid >> 6, lane = tid & 63;
    const int m = lane & 15, quad = lane >> 4;

    for (int i = tid; i < 640; i += 256) bsh[i] = f2bf(bond_emb[i]);
    // stage W1^T
    {
        const uint4* src = (const uint4*)w1t;
        for (int i = tid; i < 2048; i += 256) {
            int n = i >> 4, k8 = i & 15;
            *(uint4*)&Ws[n][k8 * 8] = src[i];
        }
    }
    // gather-aggregate phase: 16 row-processors x 16 lanes (8 cols each)
    {
        const int rp = tid >> 4, c8 = (tid & 15) * 8;
        // bond staged by all threads; make it visible before gather uses it
        __syncthreads();
#pragma unroll
        for (int it = 0; it < 4; it++) {
            int r = it * 16 + rp;
            int row = row0 + r;
            float acc[8];
            if (row < N) {
                const u16* selfp;
                if (use_emb) {
                    int t = types[row];
                    t = t < 0 ? 0 : (t > 119 ? 119 : t);
                    selfp = ebf + (size_t)t * 128;
                } else selfp = x_in + (size_t)row * 128;
                uint4 sv = *(const uint4*)(selfp + c8);
                const u16* sp = (const u16*)&sv;
#pragma unroll
                for (int i = 0; i < 8; i++) acc[i] = bf2f(sp[i]);
                int j0 = offs[row], j1 = offs[row + 1];
                for (int j = j0; j < j1; j++) {
                    int v = csr[j];
                    int src = v >> 3, tt = v & 7;
                    const u16* gsrc;
                    if (use_emb) {
                        int t2 = types[src];
                        t2 = t2 < 0 ? 0 : (t2 > 119 ? 119 : t2);
                        gsrc = ebf + (size_t)t2 * 128;
                    } else gsrc = x_in + (size_t)src * 128;
                    uint4 g = *(const uint4*)(gsrc + c8);
                    const u16* gp = (const u16*)&g;
                    const u16* bp = bsh + tt * 128 + c8;
#pragma unroll
                    for (int i = 0; i < 8; i++) {
                        float mm = bf2f(gp[i]) + bf2f(bp[i]);
                        acc[i] += (mm > 0.f ? mm : 0.f);
                    }
                }
            } else {
#pragma unroll
                for (int i = 0; i < 8; i++) acc[i] = 0.f;
            }
            uint4 ov;
            u16* op = (u16*)&ov;
#pragma unroll
            for (int i = 0; i < 8; i++) op[i] = f2bf(acc[i]);
            *(uint4*)&As[r][c8] = ov;
        }
    }
    __syncthreads();

    // mm1
    f32x4 acc[8];
#pragma unroll
    for (int c = 0; c < 8; c++) acc[c] = (f32x4){0.f, 0.f, 0.f, 0.f};
#pragma unroll
    for (int q = 0; q < 4; q++) {
        short8 a = *(const short8*)&As[wave * 16 + m][q * 32 + quad * 8];
#pragma unroll
        for (int c = 0; c < 8; c++) {
            short8 b = *(const short8*)&Ws[c * 16 + m][q * 32 + quad * 8];
            acc[c] = __builtin_amdgcn_mfma_f32_16x16x32_bf16(a, b, acc[c], 0, 0, 0);
        }
    }
    __syncthreads();
    // stage W2^T
    {
        const uint4* src = (const uint4*)w2t;
        for (int i = tid; i < 2048; i += 256) {
            int n = i >> 4, k8 = i & 15;
            *(uint4*)&Ws[n][k8 * 8] = src[i];
        }
    }
    // h = relu(acc+b1) -> As
#pragma unroll
    for (int c = 0; c < 8; c++) {
        int col = c * 16 + m;
        float bias = b1[col];
#pragma unroll
        for (int r = 0; r < 4; r++) {
            float v = acc[c][r] + bias;
            v = v > 0.f ? v : 0.f;
            As[wave * 16 + quad * 4 + r][col] = f2bf(v);
        }
    }
    __syncthreads();
    // mm2
    f32x4 acc2[8];
#pragma unroll
    for (int c = 0; c < 8; c++) acc2[c] = (f32x4){0.f, 0.f, 0.f, 0.f};
#pragma unroll
    for (int q = 0; q < 4; q++) {
        short8 a = *(const short8*)&As[wave * 16 + m][q * 32 + quad * 8];
#pragma unroll
        for (int c = 0; c < 8; c++) {
            short8 b = *(const short8*)&Ws[c * 16 + m][q * 32 + quad * 8];
            acc2[c] = __builtin_amdgcn_mfma_f32_16x16x32_bf16(a, b, acc2[c], 0, 0, 0);
        }
    }
    __syncthreads();
#pragma unroll
    for (int c = 0; c < 8; c++) {
        int col = c * 16 + m;
        float bias = b2[col];
#pragma unroll
        for (int r = 0; r < 4; r++)
            As[wave * 16 + quad * 4 + r][col] = f2bf(acc2[c][r] + bias);
    }
    __syncthreads();
    for (int i = tid; i < 1024; i += 256) {
        int r = i >> 4, c8 = (i & 15) * 8;
        int row = row0 + r;
        if (row < N) *(uint4*)(x_out + (size_t)row * 128 + c8) = *(const uint4*)&As[r][c8];
    }
}

// ---- readout mean: gm[g] = bf16(mean of x rows in segment g), vectorized
__global__ __launch_bounds__(256) void readout_mean_kernel(
    const u16* __restrict__ x, const int* __restrict__ nb,
    u16* __restrict__ gm, int N)
{
    __shared__ int range[2];
    __shared__ float part[16][128];
    int b = blockIdx.x;
    int tid = threadIdx.x;
    if (tid < 2) {
        int target = b + tid;
        int lo = 0, hi = N;
        while (lo < hi) {
            int mid = (lo + hi) >> 1;
            if (nb[mid] < target) lo = mid + 1; else hi = mid;
        }
        range[tid] = lo;
    }
    __syncthreads();
    int s = range[0], e = range[1];
    int rg = tid >> 4, c8 = (tid & 15) * 8;
    float acc[8];
#pragma unroll
    for (int i = 0; i < 8; i++) acc[i] = 0.f;
    for (int n = s + rg; n < e; n += 16) {
        uint4 v = *(const uint4*)(x + (size_t)n * 128 + c8);
        const u16* vp = (const u16*)&v;
#pragma unroll
        for (int i = 0; i < 8; i++) acc[i] += bf2f(vp[i]);
    }
#pragma unroll
    for (int i = 0; i < 8; i++) part[rg][c8 + i] = acc[i];
    __syncthreads();
    if (tid < 128) {
        float sum = 0.f;
#pragma unroll
        for (int g = 0; g < 16; g++) sum += part[g][tid];
        float cnt = (float)((e - s) > 0 ? (e - s) : 1);
        gm[(size_t)b * 128 + tid] = f2bf(sum / cnt);
    }
}

// ---- proj: out = silu(gm @ PW1 + pb1) @ PW2 + pb2   (fp32 out, 64 rows/block)
__global__ __launch_bounds__(256) void proj_kernel(
    const u16* __restrict__ gm, float* __restrict__ out,
    const u16* __restrict__ pw1t, const float* __restrict__ pb1,
    const u16* __restrict__ pw2t, const float* __restrict__ pb2, int G)
{
    __shared__ __align__(16) u16 As[64][136];
    __shared__ __align__(16) u16 Ws[128][136];
    const int tid  = threadIdx.x;
    const int row0 = blockIdx.x * 64;
    const int wave = tid >> 6, lane = tid & 63;
    const int m = lane & 15, quad = lane >> 4;

    {
        const uint4* src = (const uint4*)pw1t;
        for (int i = tid; i < 2048; i += 256) {
            int n = i >> 4, k8 = i & 15;
            *(uint4*)&Ws[n][k8 * 8] = src[i];
        }
    }
    for (int i = tid; i < 1024; i += 256) {
        int r = i >> 4, c8 = (i & 15) * 8;
        int row = row0 + r;
        uint4 ov = make_uint4(0u, 0u, 0u, 0u);
        if (row < G) ov = *(const uint4*)(gm + (size_t)row * 128 + c8);
        *(uint4*)&As[r][c8] = ov;
    }
    __syncthreads();
    f32x4 acc[8];
#pragma unroll
    for (int c = 0; c < 8; c++) acc[c] = (f32x4){0.f, 0.f, 0.f, 0.f};
#pragma unroll
    for (int q = 0; q < 4; q++) {
        short8 a = *(const short8*)&As[wave * 16 + m][q * 32 + quad * 8];
#pragma unroll
        for (int c = 0; c < 8; c++) {
            short8 b = *(const short8*)&Ws[c * 16 + m][q * 32 + quad * 8];
            acc[c] = __builtin_amdgcn_mfma_f32_16x16x32_bf16(a, b, acc[c], 0, 0, 0);
        }
    }
    __syncthreads();
    {
        const uint4* src = (const uint4*)pw2t;
        for (int i = tid; i < 2048; i += 256) {
            int n = i >> 4, k8 = i & 15;
            *(uint4*)&Ws[n][k8 * 8] = src[i];
        }
    }
#pragma unroll
    for (int c = 0; c < 8; c++) {
        int col = c * 16 + m;
        float bias = pb1[col];
#pragma unroll
        for (int r = 0; r < 4; r++) {
            float v = acc[c][r] + bias;
            v = v / (1.f + __expf(-v));   // SiLU
            As[wave * 16 + quad * 4 + r][col] = f2bf(v);
        }
    }
    __syncthreads();
    f32x4 acc2[8];
#pragma unroll
    for (int c = 0; c < 8; c++) acc2[c] = (f32x4){0.f, 0.f, 0.f, 0.f};
#pragma unroll
    for (int q = 0; q < 4; q++) {
        short8 a = *(const short8*)&As[wave * 16 + m][q * 32 + quad * 8];
#pragma unroll
        for (int c = 0; c < 8; c++) {
            short8 b = *(const short8*)&Ws[c * 16 + m][q * 32 + quad * 8];
            acc2[c] = __builtin_amdgcn_mfma_f32_16x16x32_bf16(a, b, acc2[c], 0, 0, 0);
        }
    }
#pragma unroll
    for (int c = 0; c < 8; c++) {
        int col = c * 16 + m;
        float bias = pb2[col];
#pragma unroll
        for (int r = 0; r < 4; r++) {
            int row = row0 + quad * 4 + r + wave * 16;
            if (row < G) out[(size_t)row * 128 + col] = acc2[c][r] + bias;
        }
    }
}

extern "C" void kernel_launch(void* const* d_in, const int* in_sizes, int n_in,
                              void* d_out, int out_size, void* d_ws, size_t ws_size,
                              hipStream_t stream) {
    const int*   atom_types  = (const int*)d_in[0];
    const int*   edges       = (const int*)d_in[1];
    const int*   edge_types  = (const int*)d_in[2];
    const int*   node_batch  = (const int*)d_in[3];
    const float* atom_emb    = (const float*)d_in[4];
    const float* bond_emb    = (const float*)d_in[5];
    const float* conv_w1     = (const float*)d_in[6];
    const float* conv_b1     = (const float*)d_in[7];
    const float* conv_w2     = (const float*)d_in[8];
    const float* conv_b2     = (const float*)d_in[9];
    const float* pw1         = (const float*)d_in[10];
    const float* pb1         = (const float*)d_in[11];
    const float* pw2         = (const float*)d_in[12];
    const float* pb2         = (const float*)d_in[13];
    float* out = (float*)d_out;

    const int N = in_sizes[0];
    const int E = in_sizes[2];
    const int G = out_size / HDIM;
    const int nblk = (N + SCAN_B - 1) / SCAN_B;

    size_t xA_bytes  = (size_t)N * HDIM * sizeof(u16);
    size_t xB_bytes  = (size_t)N * HDIM * sizeof(u16);
    size_t wt_bytes  = (size_t)8 * HDIM * HDIM * sizeof(u16);
    size_t ebf_bytes = (size_t)120 * HDIM * sizeof(u16);
    size_t gm_bytes  = (size_t)G * HDIM * sizeof(u16);
    size_t deg_bytes = (size_t)N * 4;
    size_t off_bytes = (size_t)(N + 1) * 4;
    size_t cur_bytes = (size_t)N * 4;
    size_t bs_bytes  = 1024 * 4;
    size_t csr_bytes = (size_t)E * 4;
    size_t need = xA_bytes + xB_bytes + wt_bytes + ebf_bytes + gm_bytes +
                  deg_bytes + off_bytes + cur_bytes + bs_bytes + csr_bytes;
    if (ws_size < need) {
        hipMemsetAsync(d_out, 0, (size_t)out_size * sizeof(float), stream);
        return;
    }
    char* p = (char*)d_ws;
    u16* xA   = (u16*)p;  p += xA_bytes;
    u16* xB   = (u16*)p;  p += xB_bytes;
    u16* wt   = (u16*)p;  p += wt_bytes;
    u16* ebf  = (u16*)p;  p += ebf_bytes;
    u16* gm   = (u16*)p;  p += gm_bytes;
    int* deg  = (int*)p;  p += deg_bytes;
    int* offs = (int*)p;  p += off_bytes;
    int* cur  = (int*)p;  p += cur_bytes;
    int* bsum = (int*)p;  p += bs_bytes;
    int* csr  = (int*)p;

    prep_kernel<<<(8 * 16384 + 120 * 128 + 255) / 256, 256, 0, stream>>>(
        conv_w1, conv_w2, pw1, pw2, atom_emb, wt, ebf);

    hipMemsetAsync(deg, 0, deg_bytes, stream);
    deg_hist_kernel<<<(E + 255) / 256, 256, 0, stream>>>(edges, deg, E, N);
    scan_block_kernel<<<nblk, SCAN_B, 0, stream>>>(deg, offs, bsum, N);
    scan_partials_kernel<<<1, 1024, 0, stream>>>(bsum, nblk);
    finalize_offs_kernel<<<(N + 255) / 256, 256, 0, stream>>>(offs, bsum, cur, N, E);
    fill_csr_kernel<<<(E + 255) / 256, 256, 0, stream>>>(edges, edge_types, cur, csr, E, N);

    const int gblocks = (N + 63) / 64;
    // layer 0: virtual x via embedding table -> xA
    gine_kernel<<<gblocks, 256, 0, stream>>>(
        xB /*unused*/, xA, atom_types, 1, ebf, offs, csr, bond_emb,
        wt + 0 * 16384, conv_b1 + 0, wt + 3 * 16384, conv_b2 + 0, N);
    // layer 1: xA -> xB
    gine_kernel<<<gblocks, 256, 0, stream>>>(
        xA, xB, atom_types, 0, ebf, offs, csr, bond_emb,
        wt + 1 * 16384, conv_b1 + 128, wt + 4 * 16384, conv_b2 + 128, N);
    // layer 2: xB -> xA
    gine_kernel<<<gblocks, 256, 0, stream>>>(
        xB, xA, atom_types, 0, ebf, offs, csr, bond_emb,
        wt + 2 * 16384, conv_b1 + 256, wt + 5 * 16384, conv_b2 + 256, N);

    readout_mean_kernel<<<G, 256, 0, stream>>>(xA, node_batch, gm, N);
    proj_kernel<<<(G + 63) / 64, 256, 0, stream>>>(
        gm, out, wt + 6 * 16384, pb1, wt + 7 * 16384, pb2, G);
}

// Round 7
// 398.375 us; speedup vs baseline: 8.7917x; 1.0972x over previous
//
#include <hip/hip_runtime.h>

typedef unsigned short u16;
typedef __attribute__((ext_vector_type(8))) short short8;
typedef __attribute__((ext_vector_type(4))) float f32x4;

#define HDIM 128
#define SCAN_B 512

__device__ __forceinline__ float bf2f(u16 v) {
    return __uint_as_float(((unsigned int)v) << 16);
}
__device__ __forceinline__ u16 f2bf(float f) {
    unsigned int u = __float_as_uint(f);
    unsigned int r = (u + 0x7FFFu + ((u >> 16) & 1u)) >> 16;  // RNE
    return (u16)r;
}

// ---- prep: transpose+bf16 8 weight mats (0-2 w1, 3-5 w2, 6 pw1, 7 pw2) + bf16 embed table
__global__ __launch_bounds__(256) void prep_kernel(
    const float* __restrict__ w1, const float* __restrict__ w2,
    const float* __restrict__ pw1, const float* __restrict__ pw2,
    const float* __restrict__ atom_emb,
    u16* __restrict__ wt, u16* __restrict__ ebf)
{
    int gid = blockIdx.x * 256 + threadIdx.x;
    if (gid < 8 * 16384) {
        int mat = gid >> 14;
        int idx = gid & 16383;
        int n = idx >> 7, k = idx & 127;
        const float* src;
        if      (mat < 3) src = w1 + mat * 16384;
        else if (mat < 6) src = w2 + (mat - 3) * 16384;
        else if (mat == 6) src = pw1;
        else               src = pw2;
        wt[gid] = f2bf(src[k * 128 + n]);
    } else {
        int i = gid - 8 * 16384;
        if (i < 120 * 128) ebf[i] = f2bf(atom_emb[i]);
    }
}

// ============ CSR build (once; edges layer-invariant) ============
__global__ __launch_bounds__(256) void deg_hist_kernel(
    const int* __restrict__ edges, int* __restrict__ deg, int E, int N)
{
    int e = blockIdx.x * 256 + threadIdx.x;
    if (e >= E) return;
    int d = edges[E + e];
    d = d < 0 ? 0 : (d >= N ? N - 1 : d);
    atomicAdd(&deg[d], 1);
}

__global__ __launch_bounds__(SCAN_B) void scan_block_kernel(
    const int* __restrict__ deg, int* __restrict__ offs, int* __restrict__ bsum, int N)
{
    __shared__ int tmp[SCAN_B];
    int t = threadIdx.x;
    int gid = blockIdx.x * SCAN_B + t;
    int v = (gid < N) ? deg[gid] : 0;
    tmp[t] = v;
    __syncthreads();
#pragma unroll
    for (int off = 1; off < SCAN_B; off <<= 1) {
        int add = (t >= off) ? tmp[t - off] : 0;
        __syncthreads();
        tmp[t] += add;
        __syncthreads();
    }
    if (gid < N) offs[gid] = tmp[t] - v;
    if (t == SCAN_B - 1) bsum[blockIdx.x] = tmp[t];
}

__global__ __launch_bounds__(1024) void scan_partials_kernel(int* __restrict__ bsum, int nblk)
{
    __shared__ int tmp[1024];
    int t = threadIdx.x;
    int v = (t < nblk) ? bsum[t] : 0;
    tmp[t] = v;
    __syncthreads();
#pragma unroll
    for (int off = 1; off < 1024; off <<= 1) {
        int add = (t >= off) ? tmp[t - off] : 0;
        __syncthreads();
        tmp[t] += add;
        __syncthreads();
    }
    if (t < nblk) bsum[t] = tmp[t] - v;
}

__global__ __launch_bounds__(256) void finalize_offs_kernel(
    int* __restrict__ offs, const int* __restrict__ bsum,
    int* __restrict__ cursor, int N, int E)
{
    int gid = blockIdx.x * 256 + threadIdx.x;
    if (gid < N) {
        int v = offs[gid] + bsum[gid / SCAN_B];
        offs[gid] = v;
        cursor[gid] = v;
    }
    if (gid == 0) offs[N] = E;
}

__global__ __launch_bounds__(256) void fill_csr_kernel(
    const int* __restrict__ edges, const int* __restrict__ etypes,
    int* __restrict__ cursor, int* __restrict__ csr, int E, int N)
{
    int e = blockIdx.x * 256 + threadIdx.x;
    if (e >= E) return;
    int s = edges[e], d = edges[E + e], t = etypes[e];
    s = s < 0 ? 0 : (s >= N ? N - 1 : s);
    d = d < 0 ? 0 : (d >= N ? N - 1 : d);
    t = t < 0 ? 0 : (t > 4 ? 4 : t);
    int pos = atomicAdd(&cursor[d], 1);
    csr[pos] = (s << 3) | t;
}

// ============ fused GINE layer: gather-agg -> MLP, 128 rows/block, 512 threads ============
// x_out = relu( bf16(x_in + sum relu(x_in[src]+bond)) @ W1 + b1 ) @ W2 + b2
// layer 0 (use_emb=1): x_in virtual: row i = ebf[clip(types[i])]
__global__ __launch_bounds__(512, 4) void gine_kernel(
    const u16* __restrict__ x_in, u16* __restrict__ x_out,
    const int* __restrict__ types, int use_emb, const u16* __restrict__ ebf,
    const int* __restrict__ offs, const int* __restrict__ csr,
    const float* __restrict__ bond_emb,
    const u16* __restrict__ w1t, const float* __restrict__ b1,
    const u16* __restrict__ w2t, const float* __restrict__ b2, int N)
{
    __shared__ __align__(16) u16 As[128][136];   // A-tile, +8 pad
    __shared__ __align__(16) u16 Ws[128][136];   // W^T tile, +8 pad
    __shared__ __align__(16) u16 bsh[5 * 128];   // bond table bf16
    const int tid  = threadIdx.x;
    const int row0 = blockIdx.x * 128;
    const int wave = tid >> 6, lane = tid & 63;
    const int m = lane & 15, quad = lane >> 4;

    for (int i = tid; i < 640; i += 512) bsh[i] = f2bf(bond_emb[i]);
    // stage W1^T
    {
        const uint4* src = (const uint4*)w1t;
        for (int i = tid; i < 2048; i += 512) {
            int n = i >> 4, k8 = i & 15;
            *(uint4*)&Ws[n][k8 * 8] = src[i];
        }
    }
    // gather-aggregate: 32 row-processors x 16 lanes (8 cols each), 4 rows each,
    // 4-way edge ILP inside each row's edge loop.
    {
        const int rp = tid >> 4, c8 = (tid & 15) * 8;
        __syncthreads();   // bsh visible
#pragma unroll
        for (int it = 0; it < 4; it++) {
            int r = it * 32 + rp;
            int row = row0 + r;
            float acc[8];
            if (row < N) {
                const u16* selfp;
                if (use_emb) {
                    int t = types[row];
                    t = t < 0 ? 0 : (t > 119 ? 119 : t);
                    selfp = ebf + (size_t)t * 128;
                } else selfp = x_in + (size_t)row * 128;
                uint4 sv = *(const uint4*)(selfp + c8);
                const u16* sp = (const u16*)&sv;
#pragma unroll
                for (int i = 0; i < 8; i++) acc[i] = bf2f(sp[i]);
                int j0 = offs[row], j1 = offs[row + 1];
                int j = j0;
                for (; j + 4 <= j1; j += 4) {          // 4 independent gathers in flight
                    int v0 = csr[j], v1 = csr[j + 1], v2 = csr[j + 2], v3 = csr[j + 3];
                    const u16* p0;
                    const u16* p1;
                    const u16* p2;
                    const u16* p3;
                    if (use_emb) {
                        int a0 = types[v0 >> 3], a1 = types[v1 >> 3], a2 = types[v2 >> 3], a3 = types[v3 >> 3];
                        a0 = a0 < 0 ? 0 : (a0 > 119 ? 119 : a0);
                        a1 = a1 < 0 ? 0 : (a1 > 119 ? 119 : a1);
                        a2 = a2 < 0 ? 0 : (a2 > 119 ? 119 : a2);
                        a3 = a3 < 0 ? 0 : (a3 > 119 ? 119 : a3);
                        p0 = ebf + (size_t)a0 * 128; p1 = ebf + (size_t)a1 * 128;
                        p2 = ebf + (size_t)a2 * 128; p3 = ebf + (size_t)a3 * 128;
                    } else {
                        p0 = x_in + (size_t)(v0 >> 3) * 128;
                        p1 = x_in + (size_t)(v1 >> 3) * 128;
                        p2 = x_in + (size_t)(v2 >> 3) * 128;
                        p3 = x_in + (size_t)(v3 >> 3) * 128;
                    }
                    uint4 g0 = *(const uint4*)(p0 + c8);
                    uint4 g1 = *(const uint4*)(p1 + c8);
                    uint4 g2 = *(const uint4*)(p2 + c8);
                    uint4 g3 = *(const uint4*)(p3 + c8);
                    const u16* q0 = (const u16*)&g0;
                    const u16* q1 = (const u16*)&g1;
                    const u16* q2 = (const u16*)&g2;
                    const u16* q3 = (const u16*)&g3;
                    const u16* b0 = bsh + (v0 & 7) * 128 + c8;
                    const u16* b1p = bsh + (v1 & 7) * 128 + c8;
                    const u16* b2p = bsh + (v2 & 7) * 128 + c8;
                    const u16* b3 = bsh + (v3 & 7) * 128 + c8;
#pragma unroll
                    for (int i = 0; i < 8; i++) {
                        float m0 = bf2f(q0[i]) + bf2f(b0[i]);
                        float m1 = bf2f(q1[i]) + bf2f(b1p[i]);
                        float m2 = bf2f(q2[i]) + bf2f(b2p[i]);
                        float m3 = bf2f(q3[i]) + bf2f(b3[i]);
                        acc[i] += (m0 > 0.f ? m0 : 0.f) + (m1 > 0.f ? m1 : 0.f)
                                + (m2 > 0.f ? m2 : 0.f) + (m3 > 0.f ? m3 : 0.f);
                    }
                }
                for (; j < j1; j++) {
                    int v = csr[j];
                    int src = v >> 3, tt = v & 7;
                    const u16* gsrc;
                    if (use_emb) {
                        int t2 = types[src];
                        t2 = t2 < 0 ? 0 : (t2 > 119 ? 119 : t2);
                        gsrc = ebf + (size_t)t2 * 128;
                    } else gsrc = x_in + (size_t)src * 128;
                    uint4 g = *(const uint4*)(gsrc + c8);
                    const u16* gp = (const u16*)&g;
                    const u16* bp = bsh + tt * 128 + c8;
#pragma unroll
                    for (int i = 0; i < 8; i++) {
                        float mm = bf2f(gp[i]) + bf2f(bp[i]);
                        acc[i] += (mm > 0.f ? mm : 0.f);
                    }
                }
            } else {
#pragma unroll
                for (int i = 0; i < 8; i++) acc[i] = 0.f;
            }
            uint4 ov;
            u16* op = (u16*)&ov;
#pragma unroll
            for (int i = 0; i < 8; i++) op[i] = f2bf(acc[i]);
            *(uint4*)&As[r][c8] = ov;
        }
    }
    __syncthreads();

    // mm1: each of 8 waves does 16 rows x 128 cols
    f32x4 acc[8];
#pragma unroll
    for (int c = 0; c < 8; c++) acc[c] = (f32x4){0.f, 0.f, 0.f, 0.f};
#pragma unroll
    for (int q = 0; q < 4; q++) {
        short8 a = *(const short8*)&As[wave * 16 + m][q * 32 + quad * 8];
#pragma unroll
        for (int c = 0; c < 8; c++) {
            short8 b = *(const short8*)&Ws[c * 16 + m][q * 32 + quad * 8];
            acc[c] = __builtin_amdgcn_mfma_f32_16x16x32_bf16(a, b, acc[c], 0, 0, 0);
        }
    }
    __syncthreads();
    // stage W2^T
    {
        const uint4* src = (const uint4*)w2t;
        for (int i = tid; i < 2048; i += 512) {
            int n = i >> 4, k8 = i & 15;
            *(uint4*)&Ws[n][k8 * 8] = src[i];
        }
    }
    // h = relu(acc+b1) -> As  (D layout: row=quad*4+r, col=lane&15)
#pragma unroll
    for (int c = 0; c < 8; c++) {
        int col = c * 16 + m;
        float bias = b1[col];
#pragma unroll
        for (int r = 0; r < 4; r++) {
            float v = acc[c][r] + bias;
            v = v > 0.f ? v : 0.f;
            As[wave * 16 + quad * 4 + r][col] = f2bf(v);
        }
    }
    __syncthreads();
    // mm2
    f32x4 acc2[8];
#pragma unroll
    for (int c = 0; c < 8; c++) acc2[c] = (f32x4){0.f, 0.f, 0.f, 0.f};
#pragma unroll
    for (int q = 0; q < 4; q++) {
        short8 a = *(const short8*)&As[wave * 16 + m][q * 32 + quad * 8];
#pragma unroll
        for (int c = 0; c < 8; c++) {
            short8 b = *(const short8*)&Ws[c * 16 + m][q * 32 + quad * 8];
            acc2[c] = __builtin_amdgcn_mfma_f32_16x16x32_bf16(a, b, acc2[c], 0, 0, 0);
        }
    }
    __syncthreads();
#pragma unroll
    for (int c = 0; c < 8; c++) {
        int col = c * 16 + m;
        float bias = b2[col];
#pragma unroll
        for (int r = 0; r < 4; r++)
            As[wave * 16 + quad * 4 + r][col] = f2bf(acc2[c][r] + bias);
    }
    __syncthreads();
    for (int i = tid; i < 2048; i += 512) {
        int r = i >> 4, c8 = (i & 15) * 8;
        int row = row0 + r;
        if (row < N) *(uint4*)(x_out + (size_t)row * 128 + c8) = *(const uint4*)&As[r][c8];
    }
}

// ---- readout mean: gm[g] = bf16(mean of x rows in segment g), vectorized
__global__ __launch_bounds__(256) void readout_mean_kernel(
    const u16* __restrict__ x, const int* __restrict__ nb,
    u16* __restrict__ gm, int N)
{
    __shared__ int range[2];
    __shared__ float part[16][128];
    int b = blockIdx.x;
    int tid = threadIdx.x;
    if (tid < 2) {
        int target = b + tid;
        int lo = 0, hi = N;
        while (lo < hi) {
            int mid = (lo + hi) >> 1;
            if (nb[mid] < target) lo = mid + 1; else hi = mid;
        }
        range[tid] = lo;
    }
    __syncthreads();
    int s = range[0], e = range[1];
    int rg = tid >> 4, c8 = (tid & 15) * 8;
    float acc[8];
#pragma unroll
    for (int i = 0; i < 8; i++) acc[i] = 0.f;
    for (int n = s + rg; n < e; n += 16) {
        uint4 v = *(const uint4*)(x + (size_t)n * 128 + c8);
        const u16* vp = (const u16*)&v;
#pragma unroll
        for (int i = 0; i < 8; i++) acc[i] += bf2f(vp[i]);
    }
#pragma unroll
    for (int i = 0; i < 8; i++) part[rg][c8 + i] = acc[i];
    __syncthreads();
    if (tid < 128) {
        float sum = 0.f;
#pragma unroll
        for (int g = 0; g < 16; g++) sum += part[g][tid];
        float cnt = (float)((e - s) > 0 ? (e - s) : 1);
        gm[(size_t)b * 128 + tid] = f2bf(sum / cnt);
    }
}

// ---- proj: out = silu(gm @ PW1 + pb1) @ PW2 + pb2   (fp32 out, 64 rows/block)
__global__ __launch_bounds__(256) void proj_kernel(
    const u16* __restrict__ gm, float* __restrict__ out,
    const u16* __restrict__ pw1t, const float* __restrict__ pb1,
    const u16* __restrict__ pw2t, const float* __restrict__ pb2, int G)
{
    __shared__ __align__(16) u16 As[64][136];
    __shared__ __align__(16) u16 Ws[128][136];
    const int tid  = threadIdx.x;
    const int row0 = blockIdx.x * 64;
    const int wave = tid >> 6, lane = tid & 63;
    const int m = lane & 15, quad = lane >> 4;

    {
        const uint4* src = (const uint4*)pw1t;
        for (int i = tid; i < 2048; i += 256) {
            int n = i >> 4, k8 = i & 15;
            *(uint4*)&Ws[n][k8 * 8] = src[i];
        }
    }
    for (int i = tid; i < 1024; i += 256) {
        int r = i >> 4, c8 = (i & 15) * 8;
        int row = row0 + r;
        uint4 ov = make_uint4(0u, 0u, 0u, 0u);
        if (row < G) ov = *(const uint4*)(gm + (size_t)row * 128 + c8);
        *(uint4*)&As[r][c8] = ov;
    }
    __syncthreads();
    f32x4 acc[8];
#pragma unroll
    for (int c = 0; c < 8; c++) acc[c] = (f32x4){0.f, 0.f, 0.f, 0.f};
#pragma unroll
    for (int q = 0; q < 4; q++) {
        short8 a = *(const short8*)&As[wave * 16 + m][q * 32 + quad * 8];
#pragma unroll
        for (int c = 0; c < 8; c++) {
            short8 b = *(const short8*)&Ws[c * 16 + m][q * 32 + quad * 8];
            acc[c] = __builtin_amdgcn_mfma_f32_16x16x32_bf16(a, b, acc[c], 0, 0, 0);
        }
    }
    __syncthreads();
    {
        const uint4* src = (const uint4*)pw2t;
        for (int i = tid; i < 2048; i += 256) {
            int n = i >> 4, k8 = i & 15;
            *(uint4*)&Ws[n][k8 * 8] = src[i];
        }
    }
#pragma unroll
    for (int c = 0; c < 8; c++) {
        int col = c * 16 + m;
        float bias = pb1[col];
#pragma unroll
        for (int r = 0; r < 4; r++) {
            float v = acc[c][r] + bias;
            v = v / (1.f + __expf(-v));   // SiLU
            As[wave * 16 + quad * 4 + r][col] = f2bf(v);
        }
    }
    __syncthreads();
    f32x4 acc2[8];
#pragma unroll
    for (int c = 0; c < 8; c++) acc2[c] = (f32x4){0.f, 0.f, 0.f, 0.f};
#pragma unroll
    for (int q = 0; q < 4; q++) {
        short8 a = *(const short8*)&As[wave * 16 + m][q * 32 + quad * 8];
#pragma unroll
        for (int c = 0; c < 8; c++) {
            short8 b = *(const short8*)&Ws[c * 16 + m][q * 32 + quad * 8];
            acc2[c] = __builtin_amdgcn_mfma_f32_16x16x32_bf16(a, b, acc2[c], 0, 0, 0);
        }
    }
#pragma unroll
    for (int c = 0; c < 8; c++) {
        int col = c * 16 + m;
        float bias = pb2[col];
#pragma unroll
        for (int r = 0; r < 4; r++) {
            int row = row0 + quad * 4 + r + wave * 16;
            if (row < G) out[(size_t)row * 128 + col] = acc2[c][r] + bias;
        }
    }
}

extern "C" void kernel_launch(void* const* d_in, const int* in_sizes, int n_in,
                              void* d_out, int out_size, void* d_ws, size_t ws_size,
                              hipStream_t stream) {
    const int*   atom_types  = (const int*)d_in[0];
    const int*   edges       = (const int*)d_in[1];
    const int*   edge_types  = (const int*)d_in[2];
    const int*   node_batch  = (const int*)d_in[3];
    const float* atom_emb    = (const float*)d_in[4];
    const float* bond_emb    = (const float*)d_in[5];
    const float* conv_w1     = (const float*)d_in[6];
    const float* conv_b1     = (const float*)d_in[7];
    const float* conv_w2     = (const float*)d_in[8];
    const float* conv_b2     = (const float*)d_in[9];
    const float* pw1         = (const float*)d_in[10];
    const float* pb1         = (const float*)d_in[11];
    const float* pw2         = (const float*)d_in[12];
    const float* pb2         = (const float*)d_in[13];
    float* out = (float*)d_out;

    const int N = in_sizes[0];
    const int E = in_sizes[2];
    const int G = out_size / HDIM;
    const int nblk = (N + SCAN_B - 1) / SCAN_B;

    size_t xA_bytes  = (size_t)N * HDIM * sizeof(u16);
    size_t xB_bytes  = (size_t)N * HDIM * sizeof(u16);
    size_t wt_bytes  = (size_t)8 * HDIM * HDIM * sizeof(u16);
    size_t ebf_bytes = (size_t)120 * HDIM * sizeof(u16);
    size_t gm_bytes  = (size_t)G * HDIM * sizeof(u16);
    size_t deg_bytes = (size_t)N * 4;
    size_t off_bytes = (size_t)(N + 1) * 4;
    size_t cur_bytes = (size_t)N * 4;
    size_t bs_bytes  = 1024 * 4;
    size_t csr_bytes = (size_t)E * 4;
    size_t need = xA_bytes + xB_bytes + wt_bytes + ebf_bytes + gm_bytes +
                  deg_bytes + off_bytes + cur_bytes + bs_bytes + csr_bytes;
    if (ws_size < need) {
        hipMemsetAsync(d_out, 0, (size_t)out_size * sizeof(float), stream);
        return;
    }
    char* p = (char*)d_ws;
    u16* xA   = (u16*)p;  p += xA_bytes;
    u16* xB   = (u16*)p;  p += xB_bytes;
    u16* wt   = (u16*)p;  p += wt_bytes;
    u16* ebf  = (u16*)p;  p += ebf_bytes;
    u16* gm   = (u16*)p;  p += gm_bytes;
    int* deg  = (int*)p;  p += deg_bytes;
    int* offs = (int*)p;  p += off_bytes;
    int* cur  = (int*)p;  p += cur_bytes;
    int* bsum = (int*)p;  p += bs_bytes;
    int* csr  = (int*)p;

    prep_kernel<<<(8 * 16384 + 120 * 128 + 255) / 256, 256, 0, stream>>>(
        conv_w1, conv_w2, pw1, pw2, atom_emb, wt, ebf);

    hipMemsetAsync(deg, 0, deg_bytes, stream);
    deg_hist_kernel<<<(E + 255) / 256, 256, 0, stream>>>(edges, deg, E, N);
    scan_block_kernel<<<nblk, SCAN_B, 0, stream>>>(deg, offs, bsum, N);
    scan_partials_kernel<<<1, 1024, 0, stream>>>(bsum, nblk);
    finalize_offs_kernel<<<(N + 255) / 256, 256, 0, stream>>>(offs, bsum, cur, N, E);
    fill_csr_kernel<<<(E + 255) / 256, 256, 0, stream>>>(edges, edge_types, cur, csr, E, N);

    const int gblocks = (N + 127) / 128;
    gine_kernel<<<gblocks, 512, 0, stream>>>(
        xB /*unused*/, xA, atom_types, 1, ebf, offs, csr, bond_emb,
        wt + 0 * 16384, conv_b1 + 0, wt + 3 * 16384, conv_b2 + 0, N);
    gine_kernel<<<gblocks, 512, 0, stream>>>(
        xA, xB, atom_types, 0, ebf, offs, csr, bond_emb,
        wt + 1 * 16384, conv_b1 + 128, wt + 4 * 16384, conv_b2 + 128, N);
    gine_kernel<<<gblocks, 512, 0, stream>>>(
        xB, xA, atom_types, 0, ebf, offs, csr, bond_emb,
        wt + 2 * 16384, conv_b1 + 256, wt + 5 * 16384, conv_b2 + 256, N);

    readout_mean_kernel<<<G, 256, 0, stream>>>(xA, node_batch, gm, N);
    proj_kernel<<<(G + 63) / 64, 256, 0, stream>>>(
        gm, out, wt + 6 * 16384, pb1, wt + 7 * 16384, pb2, G);
}

// Round 9
// 371.393 us; speedup vs baseline: 9.4304x; 1.0727x over previous
//
#include <hip/hip_runtime.h>

typedef unsigned short u16;
typedef __attribute__((ext_vector_type(8))) short short8;
typedef __attribute__((ext_vector_type(4))) float f32x4;

#define HDIM 128
#define SCAN_B 512

__device__ __forceinline__ float bf2f(u16 v) {
    return __uint_as_float(((unsigned int)v) << 16);
}
__device__ __forceinline__ u16 f2bf(float f) {
    unsigned int u = __float_as_uint(f);
    unsigned int r = (u + 0x7FFFu + ((u >> 16) & 1u)) >> 16;  // RNE
    return (u16)r;
}

// ---- prep: transpose+bf16 8 weight mats (0-2 w1, 3-5 w2, 6 pw1, 7 pw2) + bf16 embed table
__global__ __launch_bounds__(256) void prep_kernel(
    const float* __restrict__ w1, const float* __restrict__ w2,
    const float* __restrict__ pw1, const float* __restrict__ pw2,
    const float* __restrict__ atom_emb,
    u16* __restrict__ wt, u16* __restrict__ ebf)
{
    int gid = blockIdx.x * 256 + threadIdx.x;
    if (gid < 8 * 16384) {
        int mat = gid >> 14;
        int idx = gid & 16383;
        int n = idx >> 7, k = idx & 127;
        const float* src;
        if      (mat < 3) src = w1 + mat * 16384;
        else if (mat < 6) src = w2 + (mat - 3) * 16384;
        else if (mat == 6) src = pw1;
        else               src = pw2;
        wt[gid] = f2bf(src[k * 128 + n]);
    } else {
        int i = gid - 8 * 16384;
        if (i < 120 * 128) ebf[i] = f2bf(atom_emb[i]);
    }
}

// ============ CSR build (once; edges layer-invariant) ============
__global__ __launch_bounds__(256) void deg_hist_kernel(
    const int* __restrict__ edges, int* __restrict__ deg, int E, int N)
{
    int e = blockIdx.x * 256 + threadIdx.x;
    if (e >= E) return;
    int d = edges[E + e];
    d = d < 0 ? 0 : (d >= N ? N - 1 : d);
    atomicAdd(&deg[d], 1);
}

__global__ __launch_bounds__(SCAN_B) void scan_block_kernel(
    const int* __restrict__ deg, int* __restrict__ offs, int* __restrict__ bsum, int N)
{
    __shared__ int tmp[SCAN_B];
    int t = threadIdx.x;
    int gid = blockIdx.x * SCAN_B + t;
    int v = (gid < N) ? deg[gid] : 0;
    tmp[t] = v;
    __syncthreads();
#pragma unroll
    for (int off = 1; off < SCAN_B; off <<= 1) {
        int add = (t >= off) ? tmp[t - off] : 0;
        __syncthreads();
        tmp[t] += add;
        __syncthreads();
    }
    if (gid < N) offs[gid] = tmp[t] - v;
    if (t == SCAN_B - 1) bsum[blockIdx.x] = tmp[t];
}

__global__ __launch_bounds__(1024) void scan_partials_kernel(int* __restrict__ bsum, int nblk)
{
    __shared__ int tmp[1024];
    int t = threadIdx.x;
    int v = (t < nblk) ? bsum[t] : 0;
    tmp[t] = v;
    __syncthreads();
#pragma unroll
    for (int off = 1; off < 1024; off <<= 1) {
        int add = (t >= off) ? tmp[t - off] : 0;
        __syncthreads();
        tmp[t] += add;
        __syncthreads();
    }
    if (t < nblk) bsum[t] = tmp[t] - v;
}

__global__ __launch_bounds__(256) void finalize_offs_kernel(
    int* __restrict__ offs, const int* __restrict__ bsum,
    int* __restrict__ cursor, int N, int E)
{
    int gid = blockIdx.x * 256 + threadIdx.x;
    if (gid < N) {
        int v = offs[gid] + bsum[gid / SCAN_B];
        offs[gid] = v;
        cursor[gid] = v;
    }
    if (gid == 0) offs[N] = E;
}

__global__ __launch_bounds__(256) void fill_csr_kernel(
    const int* __restrict__ edges, const int* __restrict__ etypes,
    int* __restrict__ cursor, int* __restrict__ csr, int E, int N)
{
    int e = blockIdx.x * 256 + threadIdx.x;
    if (e >= E) return;
    int s = edges[e], d = edges[E + e], t = etypes[e];
    s = s < 0 ? 0 : (s >= N ? N - 1 : s);
    d = d < 0 ? 0 : (d >= N ? N - 1 : d);
    t = t < 0 ? 0 : (t > 4 ? 4 : t);
    int pos = atomicAdd(&cursor[d], 1);
    csr[pos] = (s << 3) | t;
}

// ============ fused GINE layer: gather-agg -> MLP, 128 rows/block, 512 threads ============
// Gather: 32 row-processors x 16 lanes; each rp owns 4 rows processed as TWO LOCKSTEP PAIRS
// (2 rows x k-unroll 2 = 4 independent gathers in flight; scalar predication, no local arrays).
__global__ __launch_bounds__(512, 4) void gine_kernel(
    const u16* __restrict__ x_in, u16* __restrict__ x_out,
    const int* __restrict__ types, int use_emb, const u16* __restrict__ ebf,
    const int* __restrict__ offs, const int* __restrict__ csr,
    const float* __restrict__ bond_emb,
    const u16* __restrict__ w1t, const float* __restrict__ b1,
    const u16* __restrict__ w2t, const float* __restrict__ b2, int N)
{
    __shared__ __align__(16) u16 As[128][136];   // A-tile, +8 pad
    __shared__ __align__(16) u16 Ws[128][136];   // W^T tile, +8 pad
    __shared__ __align__(16) u16 bsh[5 * 128];   // bond table bf16
    const int tid  = threadIdx.x;
    const int row0 = blockIdx.x * 128;
    const int wave = tid >> 6, lane = tid & 63;
    const int m = lane & 15, quad = lane >> 4;

    for (int i = tid; i < 640; i += 512) bsh[i] = f2bf(bond_emb[i]);
    // stage W1^T
    {
        const uint4* src = (const uint4*)w1t;
        for (int i = tid; i < 2048; i += 512) {
            int n = i >> 4, k8 = i & 15;
            *(uint4*)&Ws[n][k8 * 8] = src[i];
        }
    }
    // ---- gather-aggregate: two lockstep row-pairs per row-processor ----
    {
        const int rp = tid >> 4, c8 = (tid & 15) * 8;
        __syncthreads();   // bsh visible
        for (int pass = 0; pass < 2; pass++) {
            int rA = (pass * 2 + 0) * 32 + rp;
            int rB = (pass * 2 + 1) * 32 + rp;
            int rowA = row0 + rA, rowB = row0 + rB;
            int rcA = rowA < N ? rowA : N - 1;
            int rcB = rowB < N ? rowB : N - 1;
            const u16 *spA, *spB;
            if (use_emb) {
                int tA = types[rcA]; tA = tA < 0 ? 0 : (tA > 119 ? 119 : tA);
                int tB = types[rcB]; tB = tB < 0 ? 0 : (tB > 119 ? 119 : tB);
                spA = ebf + (size_t)tA * 128;
                spB = ebf + (size_t)tB * 128;
            } else {
                spA = x_in + (size_t)rcA * 128;
                spB = x_in + (size_t)rcB * 128;
            }
            int jbA = offs[rcA], jeA = rowA < N ? offs[rcA + 1] : jbA;
            int jbB = offs[rcB], jeB = rowB < N ? offs[rcB + 1] : jbB;
            uint4 svA = *(const uint4*)(spA + c8);
            uint4 svB = *(const uint4*)(spB + c8);
            float accA[8], accB[8];
            {
                const u16* pA = (const u16*)&svA;
                const u16* pB = (const u16*)&svB;
#pragma unroll
                for (int i = 0; i < 8; i++) { accA[i] = bf2f(pA[i]); accB[i] = bf2f(pB[i]); }
            }
            int dA = jeA - jbA, dB = jeB - jbB;
            int dmax = dA > dB ? dA : dB;
            for (int k = 0; k < dmax; k += 2) {
                bool a0 = (k    ) < dA;
                bool a1 = (k + 1) < dA;
                bool a2 = (k    ) < dB;
                bool a3 = (k + 1) < dB;
                int v0 = a0 ? csr[jbA + k]     : 0;
                int v1 = a1 ? csr[jbA + k + 1] : 0;
                int v2 = a2 ? csr[jbB + k]     : 0;
                int v3 = a3 ? csr[jbB + k + 1] : 0;
                const u16 *g0p, *g1p, *g2p, *g3p;
                if (use_emb) {
                    int t0 = types[v0 >> 3]; t0 = t0 < 0 ? 0 : (t0 > 119 ? 119 : t0);
                    int t1 = types[v1 >> 3]; t1 = t1 < 0 ? 0 : (t1 > 119 ? 119 : t1);
                    int t2 = types[v2 >> 3]; t2 = t2 < 0 ? 0 : (t2 > 119 ? 119 : t2);
                    int t3 = types[v3 >> 3]; t3 = t3 < 0 ? 0 : (t3 > 119 ? 119 : t3);
                    g0p = ebf + (size_t)t0 * 128; g1p = ebf + (size_t)t1 * 128;
                    g2p = ebf + (size_t)t2 * 128; g3p = ebf + (size_t)t3 * 128;
                } else {
                    g0p = x_in + (size_t)(v0 >> 3) * 128;
                    g1p = x_in + (size_t)(v1 >> 3) * 128;
                    g2p = x_in + (size_t)(v2 >> 3) * 128;
                    g3p = x_in + (size_t)(v3 >> 3) * 128;
                }
                uint4 g0 = *(const uint4*)(g0p + c8);   // 4 independent gathers in flight
                uint4 g1 = *(const uint4*)(g1p + c8);
                uint4 g2 = *(const uint4*)(g2p + c8);
                uint4 g3 = *(const uint4*)(g3p + c8);
                if (a0) {
                    const u16* gp = (const u16*)&g0; const u16* bp = bsh + (v0 & 7) * 128 + c8;
#pragma unroll
                    for (int i = 0; i < 8; i++) { float mm = bf2f(gp[i]) + bf2f(bp[i]); accA[i] += mm > 0.f ? mm : 0.f; }
                }
                if (a1) {
                    const u16* gp = (const u16*)&g1; const u16* bp = bsh + (v1 & 7) * 128 + c8;
#pragma unroll
                    for (int i = 0; i < 8; i++) { float mm = bf2f(gp[i]) + bf2f(bp[i]); accA[i] += mm > 0.f ? mm : 0.f; }
                }
                if (a2) {
                    const u16* gp = (const u16*)&g2; const u16* bp = bsh + (v2 & 7) * 128 + c8;
#pragma unroll
                    for (int i = 0; i < 8; i++) { float mm = bf2f(gp[i]) + bf2f(bp[i]); accB[i] += mm > 0.f ? mm : 0.f; }
                }
                if (a3) {
                    const u16* gp = (const u16*)&g3; const u16* bp = bsh + (v3 & 7) * 128 + c8;
#pragma unroll
                    for (int i = 0; i < 8; i++) { float mm = bf2f(gp[i]) + bf2f(bp[i]); accB[i] += mm > 0.f ? mm : 0.f; }
                }
            }
            uint4 ovA = make_uint4(0u, 0u, 0u, 0u), ovB = make_uint4(0u, 0u, 0u, 0u);
            if (rowA < N) {
                u16* op = (u16*)&ovA;
#pragma unroll
                for (int i = 0; i < 8; i++) op[i] = f2bf(accA[i]);
            }
            if (rowB < N) {
                u16* op = (u16*)&ovB;
#pragma unroll
                for (int i = 0; i < 8; i++) op[i] = f2bf(accB[i]);
            }
            *(uint4*)&As[rA][c8] = ovA;
            *(uint4*)&As[rB][c8] = ovB;
        }
    }
    __syncthreads();

    // mm1: each of 8 waves does 16 rows x 128 cols
    f32x4 acc[8];
#pragma unroll
    for (int c = 0; c < 8; c++) acc[c] = (f32x4){0.f, 0.f, 0.f, 0.f};
#pragma unroll
    for (int q = 0; q < 4; q++) {
        short8 a = *(const short8*)&As[wave * 16 + m][q * 32 + quad * 8];
#pragma unroll
        for (int c = 0; c < 8; c++) {
            short8 b = *(const short8*)&Ws[c * 16 + m][q * 32 + quad * 8];
            acc[c] = __builtin_amdgcn_mfma_f32_16x16x32_bf16(a, b, acc[c], 0, 0, 0);
        }
    }
    __syncthreads();
    // stage W2^T
    {
        const uint4* src = (const uint4*)w2t;
        for (int i = tid; i < 2048; i += 512) {
            int n = i >> 4, k8 = i & 15;
            *(uint4*)&Ws[n][k8 * 8] = src[i];
        }
    }
    // h = relu(acc+b1) -> As  (D layout: row=quad*4+r, col=lane&15)
#pragma unroll
    for (int c = 0; c < 8; c++) {
        int col = c * 16 + m;
        float bias = b1[col];
#pragma unroll
        for (int r = 0; r < 4; r++) {
            float v = acc[c][r] + bias;
            v = v > 0.f ? v : 0.f;
            As[wave * 16 + quad * 4 + r][col] = f2bf(v);
        }
    }
    __syncthreads();
    // mm2
    f32x4 acc2[8];
#pragma unroll
    for (int c = 0; c < 8; c++) acc2[c] = (f32x4){0.f, 0.f, 0.f, 0.f};
#pragma unroll
    for (int q = 0; q < 4; q++) {
        short8 a = *(const short8*)&As[wave * 16 + m][q * 32 + quad * 8];
#pragma unroll
        for (int c = 0; c < 8; c++) {
            short8 b = *(const short8*)&Ws[c * 16 + m][q * 32 + quad * 8];
            acc2[c] = __builtin_amdgcn_mfma_f32_16x16x32_bf16(a, b, acc2[c], 0, 0, 0);
        }
    }
    __syncthreads();
#pragma unroll
    for (int c = 0; c < 8; c++) {
        int col = c * 16 + m;
        float bias = b2[col];
#pragma unroll
        for (int r = 0; r < 4; r++)
            As[wave * 16 + quad * 4 + r][col] = f2bf(acc2[c][r] + bias);
    }
    __syncthreads();
    for (int i = tid; i < 2048; i += 512) {
        int r = i >> 4, c8 = (i & 15) * 8;
        int row = row0 + r;
        if (row < N) *(uint4*)(x_out + (size_t)row * 128 + c8) = *(const uint4*)&As[r][c8];
    }
}

// ---- readout mean: gm[g] = bf16(mean of x rows in segment g), vectorized
__global__ __launch_bounds__(256) void readout_mean_kernel(
    const u16* __restrict__ x, const int* __restrict__ nb,
    u16* __restrict__ gm, int N)
{
    __shared__ int range[2];
    __shared__ float part[16][128];
    int b = blockIdx.x;
    int tid = threadIdx.x;
    if (tid < 2) {
        int target = b + tid;
        int lo = 0, hi = N;
        while (lo < hi) {
            int mid = (lo + hi) >> 1;
            if (nb[mid] < target) lo = mid + 1; else hi = mid;
        }
        range[tid] = lo;
    }
    __syncthreads();
    int s = range[0], e = range[1];
    int rg = tid >> 4, c8 = (tid & 15) * 8;
    float acc[8];
#pragma unroll
    for (int i = 0; i < 8; i++) acc[i] = 0.f;
    for (int n = s + rg; n < e; n += 16) {
        uint4 v = *(const uint4*)(x + (size_t)n * 128 + c8);
        const u16* vp = (const u16*)&v;
#pragma unroll
        for (int i = 0; i < 8; i++) acc[i] += bf2f(vp[i]);
    }
#pragma unroll
    for (int i = 0; i < 8; i++) part[rg][c8 + i] = acc[i];
    __syncthreads();
    if (tid < 128) {
        float sum = 0.f;
#pragma unroll
        for (int g = 0; g < 16; g++) sum += part[g][tid];
        float cnt = (float)((e - s) > 0 ? (e - s) : 1);
        gm[(size_t)b * 128 + tid] = f2bf(sum / cnt);
    }
}

// ---- proj: out = silu(gm @ PW1 + pb1) @ PW2 + pb2   (fp32 out, 64 rows/block)
__global__ __launch_bounds__(256) void proj_kernel(
    const u16* __restrict__ gm, float* __restrict__ out,
    const u16* __restrict__ pw1t, const float* __restrict__ pb1,
    const u16* __restrict__ pw2t, const float* __restrict__ pb2, int G)
{
    __shared__ __align__(16) u16 As[64][136];
    __shared__ __align__(16) u16 Ws[128][136];
    const int tid  = threadIdx.x;
    const int row0 = blockIdx.x * 64;
    const int wave = tid >> 6, lane = tid & 63;
    const int m = lane & 15, quad = lane >> 4;

    {
        const uint4* src = (const uint4*)pw1t;
        for (int i = tid; i < 2048; i += 256) {
            int n = i >> 4, k8 = i & 15;
            *(uint4*)&Ws[n][k8 * 8] = src[i];
        }
    }
    for (int i = tid; i < 1024; i += 256) {
        int r = i >> 4, c8 = (i & 15) * 8;
        int row = row0 + r;
        uint4 ov = make_uint4(0u, 0u, 0u, 0u);
        if (row < G) ov = *(const uint4*)(gm + (size_t)row * 128 + c8);
        *(uint4*)&As[r][c8] = ov;
    }
    __syncthreads();
    f32x4 acc[8];
#pragma unroll
    for (int c = 0; c < 8; c++) acc[c] = (f32x4){0.f, 0.f, 0.f, 0.f};
#pragma unroll
    for (int q = 0; q < 4; q++) {
        short8 a = *(const short8*)&As[wave * 16 + m][q * 32 + quad * 8];
#pragma unroll
        for (int c = 0; c < 8; c++) {
            short8 b = *(const short8*)&Ws[c * 16 + m][q * 32 + quad * 8];
            acc[c] = __builtin_amdgcn_mfma_f32_16x16x32_bf16(a, b, acc[c], 0, 0, 0);
        }
    }
    __syncthreads();
    {
        const uint4* src = (const uint4*)pw2t;
        for (int i = tid; i < 2048; i += 256) {
            int n = i >> 4, k8 = i & 15;
            *(uint4*)&Ws[n][k8 * 8] = src[i];
        }
    }
#pragma unroll
    for (int c = 0; c < 8; c++) {
        int col = c * 16 + m;
        float bias = pb1[col];
#pragma unroll
        for (int r = 0; r < 4; r++) {
            float v = acc[c][r] + bias;
            v = v / (1.f + __expf(-v));   // SiLU
            As[wave * 16 + quad * 4 + r][col] = f2bf(v);
        }
    }
    __syncthreads();
    f32x4 acc2[8];
#pragma unroll
    for (int c = 0; c < 8; c++) acc2[c] = (f32x4){0.f, 0.f, 0.f, 0.f};
#pragma unroll
    for (int q = 0; q < 4; q++) {
        short8 a = *(const short8*)&As[wave * 16 + m][q * 32 + quad * 8];
#pragma unroll
        for (int c = 0; c < 8; c++) {
            short8 b = *(const short8*)&Ws[c * 16 + m][q * 32 + quad * 8];
            acc2[c] = __builtin_amdgcn_mfma_f32_16x16x32_bf16(a, b, acc2[c], 0, 0, 0);
        }
    }
#pragma unroll
    for (int c = 0; c < 8; c++) {
        int col = c * 16 + m;
        float bias = pb2[col];
#pragma unroll
        for (int r = 0; r < 4; r++) {
            int row = row0 + quad * 4 + r + wave * 16;
            if (row < G) out[(size_t)row * 128 + col] = acc2[c][r] + bias;
        }
    }
}

extern "C" void kernel_launch(void* const* d_in, const int* in_sizes, int n_in,
                              void* d_out, int out_size, void* d_ws, size_t ws_size,
                              hipStream_t stream) {
    const int*   atom_types  = (const int*)d_in[0];
    const int*   edges       = (const int*)d_in[1];
    const int*   edge_types  = (const int*)d_in[2];
    const int*   node_batch  = (const int*)d_in[3];
    const float* atom_emb    = (const float*)d_in[4];
    const float* bond_emb    = (const float*)d_in[5];
    const float* conv_w1     = (const float*)d_in[6];
    const float* conv_b1     = (const float*)d_in[7];
    const float* conv_w2     = (const float*)d_in[8];
    const float* conv_b2     = (const float*)d_in[9];
    const float* pw1         = (const float*)d_in[10];
    const float* pb1         = (const float*)d_in[11];
    const float* pw2         = (const float*)d_in[12];
    const float* pb2         = (const float*)d_in[13];
    float* out = (float*)d_out;

    const int N = in_sizes[0];
    const int E = in_sizes[2];
    const int G = out_size / HDIM;
    const int nblk = (N + SCAN_B - 1) / SCAN_B;

    size_t xA_bytes  = (size_t)N * HDIM * sizeof(u16);
    size_t xB_bytes  = (size_t)N * HDIM * sizeof(u16);
    size_t wt_bytes  = (size_t)8 * HDIM * HDIM * sizeof(u16);
    size_t ebf_bytes = (size_t)120 * HDIM * sizeof(u16);
    size_t gm_bytes  = (size_t)G * HDIM * sizeof(u16);
    size_t deg_bytes = (size_t)N * 4;
    size_t off_bytes = (size_t)(N + 1) * 4;
    size_t cur_bytes = (size_t)N * 4;
    size_t bs_bytes  = 1024 * 4;
    size_t csr_bytes = (size_t)E * 4;
    size_t need = xA_bytes + xB_bytes + wt_bytes + ebf_bytes + gm_bytes +
                  deg_bytes + off_bytes + cur_bytes + bs_bytes + csr_bytes;
    if (ws_size < need) {
        hipMemsetAsync(d_out, 0, (size_t)out_size * sizeof(float), stream);
        return;
    }
    char* p = (char*)d_ws;
    u16* xA   = (u16*)p;  p += xA_bytes;
    u16* xB   = (u16*)p;  p += xB_bytes;
    u16* wt   = (u16*)p;  p += wt_bytes;
    u16* ebf  = (u16*)p;  p += ebf_bytes;
    u16* gm   = (u16*)p;  p += gm_bytes;
    int* deg  = (int*)p;  p += deg_bytes;
    int* offs = (int*)p;  p += off_bytes;
    int* cur  = (int*)p;  p += cur_bytes;
    int* bsum = (int*)p;  p += bs_bytes;
    int* csr  = (int*)p;

    prep_kernel<<<(8 * 16384 + 120 * 128 + 255) / 256, 256, 0, stream>>>(
        conv_w1, conv_w2, pw1, pw2, atom_emb, wt, ebf);

    hipMemsetAsync(deg, 0, deg_bytes, stream);
    deg_hist_kernel<<<(E + 255) / 256, 256, 0, stream>>>(edges, deg, E, N);
    scan_block_kernel<<<nblk, SCAN_B, 0, stream>>>(deg, offs, bsum, N);
    scan_partials_kernel<<<1, 1024, 0, stream>>>(bsum, nblk);
    finalize_offs_kernel<<<(N + 255) / 256, 256, 0, stream>>>(offs, bsum, cur, N, E);
    fill_csr_kernel<<<(E + 255) / 256, 256, 0, stream>>>(edges, edge_types, cur, csr, E, N);

    const int gblocks = (N + 127) / 128;
    gine_kernel<<<gblocks, 512, 0, stream>>>(
        xB /*unused*/, xA, atom_types, 1, ebf, offs, csr, bond_emb,
        wt + 0 * 16384, conv_b1 + 0, wt + 3 * 16384, conv_b2 + 0, N);
    gine_kernel<<<gblocks, 512, 0, stream>>>(
        xA, xB, atom_types, 0, ebf, offs, csr, bond_emb,
        wt + 1 * 16384, conv_b1 + 128, wt + 4 * 16384, conv_b2 + 128, N);
    gine_kernel<<<gblocks, 512, 0, stream>>>(
        xB, xA, atom_types, 0, ebf, offs, csr, bond_emb,
        wt + 2 * 16384, conv_b1 + 256, wt + 5 * 16384, conv_b2 + 256, N);

    readout_mean_kernel<<<G, 256, 0, stream>>>(xA, node_batch, gm, N);
    proj_kernel<<<(G + 63) / 64, 256, 0, stream>>>(
        gm, out, wt + 6 * 16384, pb1, wt + 7 * 16384, pb2, G);
}